// Round 1
// baseline (26.903 us; speedup 1.0000x reference)
//
#include <hip/hip_runtime.h>

// out[row] = dot(x[row*768 : row*768+768], W[0:768]) + b[0]
// row = b*N + n; 768 = C*P*P. One wave (64 lanes) per row.
// Lane i loads float4 at element offsets i*4 + k*256, k=0..2 -> fully
// coalesced (64 lanes x 16B = 1024B contiguous segments).
__global__ __launch_bounds__(256) void patchconv_kernel(
    const float* __restrict__ x,
    const float* __restrict__ W,
    const float* __restrict__ b,
    float* __restrict__ out,
    int nrows) {
  const int gtid = blockIdx.x * blockDim.x + threadIdx.x;
  const int wave = gtid >> 6;
  const int lane = threadIdx.x & 63;
  if (wave >= nrows) return;

  const float4* __restrict__ xr =
      reinterpret_cast<const float4*>(x + (size_t)wave * 768);
  const float4* __restrict__ wr = reinterpret_cast<const float4*>(W);

  float sum = 0.f;
#pragma unroll
  for (int k = 0; k < 3; ++k) {
    const float4 xv = xr[lane + k * 64];
    const float4 wv = wr[lane + k * 64];
    sum += xv.x * wv.x + xv.y * wv.y + xv.z * wv.z + xv.w * wv.w;
  }

  // 64-lane wave reduction
#pragma unroll
  for (int off = 32; off > 0; off >>= 1)
    sum += __shfl_down(sum, off, 64);

  if (lane == 0) out[wave] = sum + b[0];
}

extern "C" void kernel_launch(void* const* d_in, const int* in_sizes, int n_in,
                              void* d_out, int out_size, void* d_ws, size_t ws_size,
                              hipStream_t stream) {
  const float* x = (const float*)d_in[0];   // [B, N, C, P, P] fp32
  const float* W = (const float*)d_in[1];   // [C, P, P] fp32
  const float* b = (const float*)d_in[2];   // [1] fp32
  float* out = (float*)d_out;               // [B, N] fp32

  const int nrows = out_size;               // 256*196 = 50176
  const int wavesPerBlock = 4;              // 256 threads
  const int blocks = (nrows + wavesPerBlock - 1) / wavesPerBlock;
  patchconv_kernel<<<blocks, 256, 0, stream>>>(x, W, b, out, nrows);
}